// Round 8
// baseline (1851.023 us; speedup 1.0000x reference)
//
#include <hip/hip_runtime.h>

// RNN on MI355X: h_{t+1} = tanh(table[X[:,t]] + h_t @ W_hh), T=256, B=1024, H=512.
// Round 8: stop fighting the arch-VGPR allocator. r5/r6/r7 all spilled ~64
// regs whenever W was pinned "+v" (transient addr/gather spikes > 256 cap;
// WRITE_SIZE stuck at 7-8 MB). New split keeps arch demand ~165 (margin 90):
//   sets 0..7   -> AGPR (256 = class cap), pinned "+a"  [never implicated]
//   sets 8..11  -> STREAMED from L2, 2-buffer rotation (128 KB/CU/step)
//   sets 12..15 -> LDS (128 KB, staged once)
// xh gather for step t+1 issues at the END of step t into the dead acc regs
// and flies across the barrier (vmcnt not drained) -> no step-head stall.
// f16 single-term MFMA via builtins: absmax 0.0078 (threshold 0.0534).

typedef __attribute__((ext_vector_type(4))) float f32x4;
typedef __attribute__((ext_vector_type(8))) _Float16 f16x8;

#define T_ 256
#define E_ 128
#define H_ 512
#define V_ 115

__device__ inline float tanh_fast(float x) {
  float e = __expf(-2.0f * fabsf(x));
  float t = (1.0f - e) / (1.0f + e);
  return copysignf(t, x);
}

// table[v][h] = b_h[h] + sum_e W_emb[v][e] * W_xh[e][h]   (115 x 512, f32)
__global__ void prep_table(const float* __restrict__ Wemb, const float* __restrict__ Wxh,
                           const float* __restrict__ bh, float* __restrict__ Txh) {
  int v = blockIdx.x;
  int h = threadIdx.x;
  float s = bh[h];
  const float* we = Wemb + v * E_;
#pragma unroll 8
  for (int e = 0; e < E_; ++e) s += we[e] * Wxh[e * H_ + h];
  Txh[v * H_ + h] = s;
}

// Wf layout (f16): frag (nb=n>>4, kc=k>>5) is a contiguous 1KB block of 64
// lanes x 16B; lane (lg*16+lm) holds col n=nb*16+lm, k=kc*32+lg*8..+8.
__global__ void prep_wf(const float* __restrict__ Whh, _Float16* __restrict__ Wf) {
  int idx = blockIdx.x * 256 + threadIdx.x;  // 512*512
  int k = idx >> 9, n = idx & 511;
  float w = Whh[k * H_ + n];
  int nb = n >> 4, lm = n & 15, kc = k >> 5, lg = (k >> 3) & 3, kk = k & 7;
  Wf[(((nb * 16 + kc) * 4 + lg) * 16 + lm) * 8 + kk] = (_Float16)w;
}

// W frag (f, set s) for wave with col-block base nb0: contiguous 1KB/wave
#define WG(f, s) (((const f16x8*)Wf)[(((nb0 + (f)) * 16 + (s)) << 6) + lane])

#define DECL8(s)                                                        \
  f16x8 W##s##_0 = WG(0, s), W##s##_1 = WG(1, s), W##s##_2 = WG(2, s),  \
        W##s##_3 = WG(3, s), W##s##_4 = WG(4, s), W##s##_5 = WG(5, s),  \
        W##s##_6 = WG(6, s), W##s##_7 = WG(7, s);

// One-time AGPR pin: blocks remat, forces acc-class residency (256 = cap).
#define PIN8A(s)                                                         \
  asm volatile("" : "+a"(W##s##_0), "+a"(W##s##_1), "+a"(W##s##_2),      \
                    "+a"(W##s##_3), "+a"(W##s##_4), "+a"(W##s##_5),      \
                    "+a"(W##s##_6), "+a"(W##s##_7));

#define MMB(ac, a8, wv) \
  ac = __builtin_amdgcn_mfma_f32_16x16x32_f16(a8, wv, ac, 0, 0, 0);

#define RSET(s) {                                                  \
  f16x8 a8 = *(const f16x8*)(Ah + (s) * 512 + lane * 8);           \
  MMB(acc0, a8, W##s##_0) MMB(acc1, a8, W##s##_1)                  \
  MMB(acc2, a8, W##s##_2) MMB(acc3, a8, W##s##_3)                  \
  MMB(acc4, a8, W##s##_4) MMB(acc5, a8, W##s##_5)                  \
  MMB(acc6, a8, W##s##_6) MMB(acc7, a8, W##s##_7) }

// streamed-set consume / refill (buf = f16x8[8] = 32 arch regs)
#define SSET(buf, s) {                                             \
  f16x8 a8 = *(const f16x8*)(Ah + (s) * 512 + lane * 8);           \
  MMB(acc0, a8, buf[0]) MMB(acc1, a8, buf[1])                      \
  MMB(acc2, a8, buf[2]) MMB(acc3, a8, buf[3])                      \
  MMB(acc4, a8, buf[4]) MMB(acc5, a8, buf[5])                      \
  MMB(acc6, a8, buf[6]) MMB(acc7, a8, buf[7]) }

#define SLOAD(buf, s) {                                            \
  buf[0] = WG(0, s); buf[1] = WG(1, s); buf[2] = WG(2, s);         \
  buf[3] = WG(3, s); buf[4] = WG(4, s); buf[5] = WG(5, s);         \
  buf[6] = WG(6, s); buf[7] = WG(7, s); }

#define LSET(j) {                                                  \
  f16x8 a8 = *(const f16x8*)(Ah + (12 + (j)) * 512 + lane * 8);    \
  const f16x8* wp = (const f16x8*)WL + ((w * 32 + (j) * 8) << 6) + lane; \
  f16x8 q0 = wp[0 * 64], q1 = wp[1 * 64], q2 = wp[2 * 64], q3 = wp[3 * 64]; \
  MMB(acc0, a8, q0) MMB(acc1, a8, q1) MMB(acc2, a8, q2) MMB(acc3, a8, q3)   \
  f16x8 q4 = wp[4 * 64], q5 = wp[5 * 64], q6 = wp[6 * 64], q7 = wp[7 * 64]; \
  MMB(acc4, a8, q4) MMB(acc5, a8, q5) MMB(acc6, a8, q6) MMB(acc7, a8, q7) }

// epilogue for frag f, then immediately refill acc##f with next step's xh
// (loads fly across the following barrier; acc regs were dead anyway).
#define EPI(f) {                                                   \
  int n = w * 128 + (f) * 16 + lm;                                 \
  int bidx = (n >> 5) * 512 + ((n >> 3) & 3) * 128 + (n & 7);      \
  _Pragma("unroll")                                                \
  for (int r = 0; r < 4; ++r) {                                    \
    int m = lg * 4 + r;                                            \
    float hv = tanh_fast(acc##f[r]);                               \
    Ah[bidx + m * 8] = (_Float16)hv;                               \
    if (t == T_ - 1) Hfin[(r0 + m) * H_ + n] = hv;                 \
  }                                                                \
  acc##f[0] = tg0[(f) * 16]; acc##f[1] = tg1[(f) * 16];            \
  acc##f[2] = tg2[(f) * 16]; acc##f[3] = tg3[(f) * 16]; }

__global__ __launch_bounds__(256, 1) __attribute__((amdgpu_waves_per_eu(1, 1)))
void rnn_main(const int* __restrict__ X, const float* __restrict__ Txh,
              const _Float16* __restrict__ Wf, const float* __restrict__ Why,
              const float* __restrict__ by, float* __restrict__ Hfin,
              float* __restrict__ out) {
  __shared__ _Float16 Ah[16 * H_];        // 16 KB: h_t (f16, A-frag layout)
  __shared__ _Float16 WL[65536];          // 128 KB: W sets 12..15, all 4 waves
  __shared__ unsigned char sXb[16 * T_];  // 4 KB: X rows as bytes (vocab<256)

  const int tid = threadIdx.x;
  const int lane = tid & 63;
  const int w = tid >> 6;          // wave 0..3; owns cols [w*128, w*128+128)
  const int nb0 = w * 8;
  const int r0 = blockIdx.x * 16;
  const int lm = lane & 15;
  const int lg = lane >> 4;

  for (int i = tid; i < 16 * H_ / 2; i += 256) ((int*)Ah)[i] = 0;
  for (int i = tid; i < 16 * T_; i += 256)
    sXb[i] = (unsigned char)X[(r0 + (i >> 8)) * T_ + (i & 255)];
  // Stage W sets 12..15 for all waves into LDS (one time, 128 KB).
  for (int i = tid; i < 8192; i += 256) {
    int frag = i >> 6, ln = i & 63;
    int fw = frag >> 5, j = (frag >> 3) & 3, f = frag & 7;
    int nb = fw * 8 + f;
    ((f16x8*)WL)[(frag << 6) + ln] =
        ((const f16x8*)Wf)[((nb * 16 + 12 + j) << 6) + ln];
  }

  // AGPR-resident W: sets 0..7 (exactly the 256-reg acc class cap), pinned.
  DECL8(0) DECL8(1) DECL8(2) DECL8(3) DECL8(4) DECL8(5) DECL8(6) DECL8(7)
  PIN8A(0) PIN8A(1) PIN8A(2) PIN8A(3) PIN8A(4) PIN8A(5) PIN8A(6) PIN8A(7)

  // Prime the stream double-buffer: sa <- set 8, sb <- set 9.
  f16x8 sa[8], sb[8];
  SLOAD(sa, 8)
  SLOAD(sb, 9)

  // Prologue xh gather for t=0 straight into acc (the MFMA C-operand).
  f32x4 acc0, acc1, acc2, acc3, acc4, acc5, acc6, acc7;
  {
    const float* g0 = Txh + (int)sXb[(lg * 4 + 0) * T_] * H_ + w * 128 + lm;
    const float* g1 = Txh + (int)sXb[(lg * 4 + 1) * T_] * H_ + w * 128 + lm;
    const float* g2 = Txh + (int)sXb[(lg * 4 + 2) * T_] * H_ + w * 128 + lm;
    const float* g3 = Txh + (int)sXb[(lg * 4 + 3) * T_] * H_ + w * 128 + lm;
#define GATH0(f) { acc##f[0]=g0[(f)*16]; acc##f[1]=g1[(f)*16]; \
                   acc##f[2]=g2[(f)*16]; acc##f[3]=g3[(f)*16]; }
    GATH0(0) GATH0(1) GATH0(2) GATH0(3) GATH0(4) GATH0(5) GATH0(6) GATH0(7)
#undef GATH0
  }

  __syncthreads();

  for (int t = 0; t < T_; ++t) {
    // next-step X indices + gather pointers (sXb is read-only; safe anytime)
    int tn = (t + 1) & (T_ - 1);
    const float* tg0 = Txh + (int)sXb[(lg * 4 + 0) * T_ + tn] * H_ + w * 128 + lm;
    const float* tg1 = Txh + (int)sXb[(lg * 4 + 1) * T_ + tn] * H_ + w * 128 + lm;
    const float* tg2 = Txh + (int)sXb[(lg * 4 + 2) * T_ + tn] * H_ + w * 128 + lm;
    const float* tg3 = Txh + (int)sXb[(lg * 4 + 3) * T_ + tn] * H_ + w * 128 + lm;

    // Stream phase A: consume last step's prefetch, issue this step's.
    SSET(sa, 8)   SLOAD(sa, 10)
    SSET(sb, 9)   SLOAD(sb, 11)

    // AGPR phase (zero memory traffic) hides the set-10/11 loads.
    RSET(0) RSET(1) RSET(2) RSET(3) RSET(4) RSET(5) RSET(6) RSET(7)

    // Stream phase B: consume 10/11, issue NEXT step's 8/9 (fly over barrier).
    SSET(sa, 10)  SLOAD(sa, 8)
    SSET(sb, 11)  SLOAD(sb, 9)

    // LDS-resident sets 12..15 (hides the next-step stream loads).
    LSET(0) LSET(1) LSET(2) LSET(3)

    asm volatile("s_waitcnt lgkmcnt(0)" ::: "memory");
    __builtin_amdgcn_s_barrier();   // all A-reads done; safe to overwrite Ah

    // tanh + scatter new h; refill acc with next step's xh (crosses barrier)
    EPI(0) EPI(1) EPI(2) EPI(3) EPI(4) EPI(5) EPI(6) EPI(7)

    asm volatile("s_waitcnt lgkmcnt(0)" ::: "memory");
    __builtin_amdgcn_s_barrier();   // new h visible for next step
  }

  __syncthreads();  // full drain (Hfin stores, dangling prefetches)

  // logits = h_T @ W_hy + b_y for this block's 16 rows
  for (int idx = tid; idx < 16 * V_; idx += 256) {
    int m = idx / V_, v = idx - m * V_;
    const float* hp = Hfin + (r0 + m) * H_;
    float s = by[v];
#pragma unroll 8
    for (int k = 0; k < H_; ++k) s += hp[k] * Why[k * V_ + v];
    out[(r0 + m) * V_ + v] = s;
  }
}

extern "C" void kernel_launch(void* const* d_in, const int* in_sizes, int n_in,
                              void* d_out, int out_size, void* d_ws, size_t ws_size,
                              hipStream_t stream) {
  const int* X = (const int*)d_in[0];         // [1024,256] int32
  const float* Wemb = (const float*)d_in[1];  // [115,128]
  const float* Wxh = (const float*)d_in[2];   // [128,512]
  const float* Whh = (const float*)d_in[3];   // [512,512]
  const float* bh = (const float*)d_in[4];    // [512]
  const float* Why = (const float*)d_in[5];   // [512,115]
  const float* by = (const float*)d_in[6];    // [115]
  float* out = (float*)d_out;                 // [1024,115]

  char* ws = (char*)d_ws;
  float* Txh = (float*)ws;                        // 235,520 B
  _Float16* Wf = (_Float16*)(ws + 256 * 1024);    // 512 KB
  float* Hfin = (float*)(ws + 1024 * 1024);       // 2 MB

  prep_table<<<dim3(V_), dim3(H_), 0, stream>>>(Wemb, Wxh, bh, Txh);
  prep_wf<<<dim3(1024), dim3(256), 0, stream>>>(Whh, Wf);
  rnn_main<<<dim3(64), dim3(256), 0, stream>>>(X, Txh, Wf, Why, by, Hfin, out);
}

// Round 9
// 1278.976 us; speedup vs baseline: 1.4473x; 1.4473x over previous
//
#include <hip/hip_runtime.h>

// RNN on MI355X: h_{t+1} = tanh(table[X[:,t]] + h_t @ W_hh), T=256, B=1024, H=512.
// Round 9: feasible-by-construction residency. Evidence r5-r8: the RA never
// grants >256 regs/wave total (VGPR_Count pinned at 256, spill scaling with
// the overflow). So: 8 waves x 64 cols, per-wave ask = 128 AGPR (W sets 0..7,
// pinned) + ~106 arch = 234 <= 256. Sets 12..15 in LDS (128 KB); sets 8..11
// streamed from L2 (128 KB/CU/step, double-buffer). 2 waves/SIMD doubles TLP.
// f16 single-term MFMA via builtins: absmax ~0.0078 (threshold 0.0534).

typedef __attribute__((ext_vector_type(4))) float f32x4;
typedef __attribute__((ext_vector_type(8))) _Float16 f16x8;

#define T_ 256
#define E_ 128
#define H_ 512
#define V_ 115

__device__ inline float tanh_fast(float x) {
  float e = __expf(-2.0f * fabsf(x));
  float t = (1.0f - e) / (1.0f + e);
  return copysignf(t, x);
}

// table[v][h] = b_h[h] + sum_e W_emb[v][e] * W_xh[e][h]   (115 x 512, f32)
__global__ void prep_table(const float* __restrict__ Wemb, const float* __restrict__ Wxh,
                           const float* __restrict__ bh, float* __restrict__ Txh) {
  int v = blockIdx.x;
  int h = threadIdx.x;
  float s = bh[h];
  const float* we = Wemb + v * E_;
#pragma unroll 8
  for (int e = 0; e < E_; ++e) s += we[e] * Wxh[e * H_ + h];
  Txh[v * H_ + h] = s;
}

// Wf layout (f16): frag (nb=n>>4, kc=k>>5) is a contiguous 1KB block of 64
// lanes x 16B; lane (lg*16+lm) holds col n=nb*16+lm, k=kc*32+lg*8..+8.
__global__ void prep_wf(const float* __restrict__ Whh, _Float16* __restrict__ Wf) {
  int idx = blockIdx.x * 256 + threadIdx.x;  // 512*512
  int k = idx >> 9, n = idx & 511;
  float w = Whh[k * H_ + n];
  int nb = n >> 4, lm = n & 15, kc = k >> 5, lg = (k >> 3) & 3, kk = k & 7;
  Wf[(((nb * 16 + kc) * 4 + lg) * 16 + lm) * 8 + kk] = (_Float16)w;
}

// W frag (f, set s) for wave with col-block base nb0: contiguous 1KB/wave
#define WG(f, s) (((const f16x8*)Wf)[(((nb0 + (f)) * 16 + (s)) << 6) + lane])

// Per-wave AGPR-resident W: sets 0..7 x 4 frags = 128 AGPRs.
#define DECL4(s)                                                        \
  f16x8 W##s##_0 = WG(0, s), W##s##_1 = WG(1, s),                       \
        W##s##_2 = WG(2, s), W##s##_3 = WG(3, s);
#define PIN4A(s)                                                        \
  asm volatile("" : "+a"(W##s##_0), "+a"(W##s##_1),                     \
                    "+a"(W##s##_2), "+a"(W##s##_3));

#define MMB(ac, a8, wv) \
  ac = __builtin_amdgcn_mfma_f32_16x16x32_f16(a8, wv, ac, 0, 0, 0);

#define RSET(s) {                                                  \
  f16x8 a8 = *(const f16x8*)(Ah + (s) * 512 + lane * 8);           \
  MMB(acc0, a8, W##s##_0) MMB(acc1, a8, W##s##_1)                  \
  MMB(acc2, a8, W##s##_2) MMB(acc3, a8, W##s##_3) }

// streamed-set consume / refill (buf = f16x8[4] = 16 arch regs)
#define SSET(buf, s) {                                             \
  f16x8 a8 = *(const f16x8*)(Ah + (s) * 512 + lane * 8);           \
  MMB(acc0, a8, buf[0]) MMB(acc1, a8, buf[1])                      \
  MMB(acc2, a8, buf[2]) MMB(acc3, a8, buf[3]) }

#define SLOAD(buf, s) {                                            \
  buf[0] = WG(0, s); buf[1] = WG(1, s);                            \
  buf[2] = WG(2, s); buf[3] = WG(3, s); }

// LDS-resident sets 12..15: block index bi = w*16 + j*4 + f (1KB each)
#define LSET(j) {                                                  \
  f16x8 a8 = *(const f16x8*)(Ah + (12 + (j)) * 512 + lane * 8);    \
  const f16x8* wp = (const f16x8*)WL + ((w * 16 + (j) * 4) << 6) + lane; \
  f16x8 q0 = wp[0], q1 = wp[64], q2 = wp[128], q3 = wp[192];       \
  MMB(acc0, a8, q0) MMB(acc1, a8, q1)                              \
  MMB(acc2, a8, q2) MMB(acc3, a8, q3) }

#define EPI(f) {                                                   \
  int n = w * 64 + (f) * 16 + lm;                                  \
  int bidx = (n >> 5) * 512 + ((n >> 3) & 3) * 128 + (n & 7);      \
  _Pragma("unroll")                                                \
  for (int r = 0; r < 4; ++r) {                                    \
    int m = lg * 4 + r;                                            \
    float hv = tanh_fast(acc##f[r]);                               \
    Ah[bidx + m * 8] = (_Float16)hv;                               \
    if (t == T_ - 1) Hfin[(r0 + m) * H_ + n] = hv;                 \
  } }

__global__ __launch_bounds__(512, 2) __attribute__((amdgpu_waves_per_eu(2, 2)))
void rnn_main(const int* __restrict__ X, const float* __restrict__ Txh,
              const _Float16* __restrict__ Wf, const float* __restrict__ Why,
              const float* __restrict__ by, float* __restrict__ Hfin,
              float* __restrict__ out) {
  __shared__ _Float16 Ah[16 * H_];        // 16 KB: h_t (f16, A-frag layout)
  __shared__ _Float16 WL[65536];          // 128 KB: W sets 12..15, all waves
  __shared__ unsigned char sXb[16 * T_];  // 4 KB: X rows as bytes (vocab<256)

  const int tid = threadIdx.x;
  const int lane = tid & 63;
  const int w = tid >> 6;          // wave 0..7; owns cols [w*64, w*64+64)
  const int nb0 = w * 4;
  const int r0 = blockIdx.x * 16;
  const int lm = lane & 15;
  const int lg = lane >> 4;

  for (int i = tid; i < 16 * H_ / 2; i += 512) ((int*)Ah)[i] = 0;
  for (int i = tid; i < 16 * T_; i += 512)
    sXb[i] = (unsigned char)X[(r0 + (i >> 8)) * T_ + (i & 255)];
  // Stage W sets 12..15 into LDS (one time, 128 KB). bi = w*16 + j*4 + f.
  for (int i = tid; i < 8192; i += 512) {
    int bi = i >> 6, ln = i & 63;
    int w8 = bi >> 4, rem = bi & 15, j = rem >> 2, f = rem & 3;
    int nb = w8 * 4 + f;
    ((f16x8*)WL)[(bi << 6) + ln] =
        ((const f16x8*)Wf)[((nb * 16 + 12 + j) << 6) + ln];
  }

  // AGPR-resident W: sets 0..7 -> 128 AGPRs/wave, loaded once, pinned.
  DECL4(0) DECL4(1) DECL4(2) DECL4(3) DECL4(4) DECL4(5) DECL4(6) DECL4(7)
  PIN4A(0) PIN4A(1) PIN4A(2) PIN4A(3) PIN4A(4) PIN4A(5) PIN4A(6) PIN4A(7)

  // Prime the stream double-buffer: sa <- set 8, sb <- set 9.
  f16x8 sa[4], sb[4];
  SLOAD(sa, 8)
  SLOAD(sb, 9)

  __syncthreads();

  // X indices for t=0 (prefetched each step thereafter)
  int vx0 = sXb[(lg * 4 + 0) * T_];
  int vx1 = sXb[(lg * 4 + 1) * T_];
  int vx2 = sXb[(lg * 4 + 2) * T_];
  int vx3 = sXb[(lg * 4 + 3) * T_];

  for (int t = 0; t < T_; ++t) {
    // acc := xh  (gather straight into the MFMA C-operand)
    f32x4 acc0, acc1, acc2, acc3;
    {
      const float* g0 = Txh + vx0 * H_ + w * 64 + lm;
      const float* g1 = Txh + vx1 * H_ + w * 64 + lm;
      const float* g2 = Txh + vx2 * H_ + w * 64 + lm;
      const float* g3 = Txh + vx3 * H_ + w * 64 + lm;
      acc0[0]=g0[0];  acc0[1]=g1[0];  acc0[2]=g2[0];  acc0[3]=g3[0];
      acc1[0]=g0[16]; acc1[1]=g1[16]; acc1[2]=g2[16]; acc1[3]=g3[16];
      acc2[0]=g0[32]; acc2[1]=g1[32]; acc2[2]=g2[32]; acc2[3]=g3[32];
      acc3[0]=g0[48]; acc3[1]=g1[48]; acc3[2]=g2[48]; acc3[3]=g3[48];
    }
    // prefetch next step's X indices
    {
      int tn = (t + 1) & (T_ - 1);
      vx0 = sXb[(lg * 4 + 0) * T_ + tn];
      vx1 = sXb[(lg * 4 + 1) * T_ + tn];
      vx2 = sXb[(lg * 4 + 2) * T_ + tn];
      vx3 = sXb[(lg * 4 + 3) * T_ + tn];
    }

    // Stream phase A: consume last prefetch, issue this step's second half.
    SSET(sa, 8)   SLOAD(sa, 10)
    SSET(sb, 9)   SLOAD(sb, 11)

    // AGPR phase (zero memory traffic) hides the set-10/11 loads.
    RSET(0) RSET(1) RSET(2) RSET(3) RSET(4) RSET(5) RSET(6) RSET(7)

    // Stream phase B: consume 10/11, issue NEXT step's 8/9.
    SSET(sa, 10)  SLOAD(sa, 8)
    SSET(sb, 11)  SLOAD(sb, 9)

    // LDS-resident sets 12..15.
    LSET(0) LSET(1) LSET(2) LSET(3)

    __syncthreads();  // all A-reads done; safe to overwrite Ah

    EPI(0) EPI(1) EPI(2) EPI(3)

    __syncthreads();  // new h visible for next step
  }

  // logits = h_T @ W_hy + b_y for this block's 16 rows
  for (int idx = tid; idx < 16 * V_; idx += 512) {
    int m = idx / V_, v = idx - m * V_;
    const float* hp = Hfin + (r0 + m) * H_;
    float s = by[v];
#pragma unroll 8
    for (int k = 0; k < H_; ++k) s += hp[k] * Why[k * V_ + v];
    out[(r0 + m) * V_ + v] = s;
  }
}

extern "C" void kernel_launch(void* const* d_in, const int* in_sizes, int n_in,
                              void* d_out, int out_size, void* d_ws, size_t ws_size,
                              hipStream_t stream) {
  const int* X = (const int*)d_in[0];         // [1024,256] int32
  const float* Wemb = (const float*)d_in[1];  // [115,128]
  const float* Wxh = (const float*)d_in[2];   // [128,512]
  const float* Whh = (const float*)d_in[3];   // [512,512]
  const float* bh = (const float*)d_in[4];    // [512]
  const float* Why = (const float*)d_in[5];   // [512,115]
  const float* by = (const float*)d_in[6];    // [115]
  float* out = (float*)d_out;                 // [1024,115]

  char* ws = (char*)d_ws;
  float* Txh = (float*)ws;                        // 235,520 B
  _Float16* Wf = (_Float16*)(ws + 256 * 1024);    // 512 KB
  float* Hfin = (float*)(ws + 1024 * 1024);       // 2 MB

  prep_table<<<dim3(V_), dim3(H_), 0, stream>>>(Wemb, Wxh, bh, Txh);
  prep_wf<<<dim3(1024), dim3(256), 0, stream>>>(Whh, Wf);
  rnn_main<<<dim3(64), dim3(512), 0, stream>>>(X, Txh, Wf, Why, by, Hfin, out);
}

// Round 10
// 984.247 us; speedup vs baseline: 1.8806x; 1.2994x over previous
//
#include <hip/hip_runtime.h>

// RNN on MI355X: h_{t+1} = tanh(table[X[:,t]] + h_t @ W_hh), T=256, B=1024, H=512.
// Round 10: ask BELOW the empirical spill line. r5-r9 spill magnitude tracked
// (total regs/wave - ~200): r9's 128a+110v=238 spilled ~57. New split:
//   sets 0..5   -> AGPR (96 regs/wave), pinned "+a"
//   sets 6..11  -> streamed from L2 (192 KB/CU/step, 2-buf, cross-barrier)
//   sets 12..15 -> LDS (128 KB, staged once)
// Ask ~= 96a + ~110v = 206/wave x 8 waves < 2048/CU pool. Hfin ELIMINATED
// (logits read h_T from Ah in LDS): -2MB writes, -per-step branch+addresses.
// Diagnostic: rnn_main WRITE_SIZE ~0.47MB = spill gone; >=2MB = still spilling.
// f16 single-term MFMA via builtins: absmax ~0.0078 (threshold 0.0534).

typedef __attribute__((ext_vector_type(4))) float f32x4;
typedef __attribute__((ext_vector_type(8))) _Float16 f16x8;

#define T_ 256
#define E_ 128
#define H_ 512
#define V_ 115

__device__ inline float tanh_fast(float x) {
  float e = __expf(-2.0f * fabsf(x));
  float t = (1.0f - e) / (1.0f + e);
  return copysignf(t, x);
}

// lgkm-only barrier: global (W-stream) loads stay in flight across it.
__device__ __forceinline__ void sync_lgkm() {
  asm volatile("s_waitcnt lgkmcnt(0)" ::: "memory");
  __builtin_amdgcn_s_barrier();
}

// table[v][h] = b_h[h] + sum_e W_emb[v][e] * W_xh[e][h]   (115 x 512, f32)
__global__ void prep_table(const float* __restrict__ Wemb, const float* __restrict__ Wxh,
                           const float* __restrict__ bh, float* __restrict__ Txh) {
  int v = blockIdx.x;
  int h = threadIdx.x;
  float s = bh[h];
  const float* we = Wemb + v * E_;
#pragma unroll 8
  for (int e = 0; e < E_; ++e) s += we[e] * Wxh[e * H_ + h];
  Txh[v * H_ + h] = s;
}

// Wf layout (f16): frag (nb=n>>4, kc=k>>5) is a contiguous 1KB block of 64
// lanes x 16B; lane (lg*16+lm) holds col n=nb*16+lm, k=kc*32+lg*8..+8.
__global__ void prep_wf(const float* __restrict__ Whh, _Float16* __restrict__ Wf) {
  int idx = blockIdx.x * 256 + threadIdx.x;  // 512*512
  int k = idx >> 9, n = idx & 511;
  float w = Whh[k * H_ + n];
  int nb = n >> 4, lm = n & 15, kc = k >> 5, lg = (k >> 3) & 3, kk = k & 7;
  Wf[(((nb * 16 + kc) * 4 + lg) * 16 + lm) * 8 + kk] = (_Float16)w;
}

// W frag (f, set s) for wave with col-block base nb0: contiguous 1KB/wave
#define WG(f, s) (((const f16x8*)Wf)[(((nb0 + (f)) * 16 + (s)) << 6) + lane])

// AGPR-resident W: sets 0..5 x 4 frags = 96 AGPRs/wave.
#define DECL4(s)                                                        \
  f16x8 W##s##_0 = WG(0, s), W##s##_1 = WG(1, s),                       \
        W##s##_2 = WG(2, s), W##s##_3 = WG(3, s);
#define PIN4A(s)                                                        \
  asm volatile("" : "+a"(W##s##_0), "+a"(W##s##_1),                     \
                    "+a"(W##s##_2), "+a"(W##s##_3));

#define MMB(ac, a8, wv) \
  ac = __builtin_amdgcn_mfma_f32_16x16x32_f16(a8, wv, ac, 0, 0, 0);

#define RSET(s) {                                                  \
  f16x8 a8 = *(const f16x8*)(Ah + (s) * 512 + lane * 8);           \
  MMB(acc0, a8, W##s##_0) MMB(acc1, a8, W##s##_1)                  \
  MMB(acc2, a8, W##s##_2) MMB(acc3, a8, W##s##_3) }

// streamed-set consume / refill (buf = f16x8[4] = 16 arch regs)
#define SSET(buf, s) {                                             \
  f16x8 a8 = *(const f16x8*)(Ah + (s) * 512 + lane * 8);           \
  MMB(acc0, a8, buf[0]) MMB(acc1, a8, buf[1])                      \
  MMB(acc2, a8, buf[2]) MMB(acc3, a8, buf[3]) }

#define SLOAD(buf, s) {                                            \
  buf[0] = WG(0, s); buf[1] = WG(1, s);                            \
  buf[2] = WG(2, s); buf[3] = WG(3, s); }

// LDS-resident sets 12..15 (bi = w*16 + j*4 + f); 2-reg-pair temps.
#define LSET(j) {                                                  \
  f16x8 a8 = *(const f16x8*)(Ah + (12 + (j)) * 512 + lane * 8);    \
  const f16x8* wp = (const f16x8*)WL + ((w * 16 + (j) * 4) << 6) + lane; \
  { f16x8 q0 = wp[0],   q1 = wp[64];  MMB(acc0, a8, q0) MMB(acc1, a8, q1) } \
  { f16x8 q2 = wp[128], q3 = wp[192]; MMB(acc2, a8, q2) MMB(acc3, a8, q3) } }

// tanh + scatter new h into A-frag layout (no global stores).
#define EPI(f) {                                                   \
  int n = w * 64 + (f) * 16 + lm;                                  \
  int bidx = (n >> 5) * 512 + ((n >> 3) & 3) * 128 + (n & 7);      \
  _Pragma("unroll")                                                \
  for (int r = 0; r < 4; ++r) {                                    \
    float hv = tanh_fast(acc##f[r]);                               \
    Ah[bidx + (lg * 4 + r) * 8] = (_Float16)hv;                    \
  } }

__global__ __launch_bounds__(512, 2) __attribute__((amdgpu_waves_per_eu(2, 2)))
void rnn_main(const int* __restrict__ X, const float* __restrict__ Txh,
              const _Float16* __restrict__ Wf, const float* __restrict__ Why,
              const float* __restrict__ by, float* __restrict__ out) {
  __shared__ _Float16 Ah[16 * H_];        // 16 KB: h_t (f16, A-frag layout)
  __shared__ _Float16 WL[65536];          // 128 KB: W sets 12..15, all waves
  __shared__ unsigned char sXb[16 * T_];  // 4 KB: X rows as bytes (vocab<256)

  const int tid = threadIdx.x;
  const int lane = tid & 63;
  const int w = tid >> 6;          // wave 0..7; owns cols [w*64, w*64+64)
  const int nb0 = w * 4;
  const int r0 = blockIdx.x * 16;
  const int lm = lane & 15;
  const int lg = lane >> 4;

  for (int i = tid; i < 16 * H_ / 2; i += 512) ((int*)Ah)[i] = 0;
  for (int i = tid; i < 16 * T_; i += 512)
    sXb[i] = (unsigned char)X[(r0 + (i >> 8)) * T_ + (i & 255)];
  // Stage W sets 12..15 into LDS (one time, 128 KB). bi = w*16 + j*4 + f.
  for (int i = tid; i < 8192; i += 512) {
    int bi = i >> 6, ln = i & 63;
    int w8 = bi >> 4, rem = bi & 15, j = rem >> 2, f = rem & 3;
    int nb = w8 * 4 + f;
    ((f16x8*)WL)[(bi << 6) + ln] =
        ((const f16x8*)Wf)[((nb * 16 + 12 + j) << 6) + ln];
  }

  // AGPR-resident W: sets 0..5 -> 96 AGPRs/wave, loaded once, pinned.
  DECL4(0) DECL4(1) DECL4(2) DECL4(3) DECL4(4) DECL4(5)
  PIN4A(0) PIN4A(1) PIN4A(2) PIN4A(3) PIN4A(4) PIN4A(5)

  // Prime the stream double-buffer: sa <- set 6, sb <- set 7.
  f16x8 sa[4], sb[4];
  SLOAD(sa, 6)
  SLOAD(sb, 7)

  // per-lane bases (loop-invariant)
  const float* txl = Txh + w * 64 + lm;

  __syncthreads();

  // X indices for t=0 (prefetched each step thereafter)
  int vx0 = sXb[(lg * 4 + 0) * T_];
  int vx1 = sXb[(lg * 4 + 1) * T_];
  int vx2 = sXb[(lg * 4 + 2) * T_];
  int vx3 = sXb[(lg * 4 + 3) * T_];

  for (int t = 0; t < T_; ++t) {
    // acc := xh  (gather straight into the MFMA C-operand)
    f32x4 acc0, acc1, acc2, acc3;
    {
      const float* g0 = txl + vx0 * H_;
      const float* g1 = txl + vx1 * H_;
      const float* g2 = txl + vx2 * H_;
      const float* g3 = txl + vx3 * H_;
      acc0[0]=g0[0];  acc0[1]=g1[0];  acc0[2]=g2[0];  acc0[3]=g3[0];
      acc1[0]=g0[16]; acc1[1]=g1[16]; acc1[2]=g2[16]; acc1[3]=g3[16];
      acc2[0]=g0[32]; acc2[1]=g1[32]; acc2[2]=g2[32]; acc2[3]=g3[32];
      acc3[0]=g0[48]; acc3[1]=g1[48]; acc3[2]=g2[48]; acc3[3]=g3[48];
    }
    // prefetch next step's X indices
    {
      int tn = (t + 1) & (T_ - 1);
      vx0 = sXb[(lg * 4 + 0) * T_ + tn];
      vx1 = sXb[(lg * 4 + 1) * T_ + tn];
      vx2 = sXb[(lg * 4 + 2) * T_ + tn];
      vx3 = sXb[(lg * 4 + 3) * T_ + tn];
    }

    // Stream rotation: consume one set, immediately issue the +2 set.
    SSET(sa, 6)   SLOAD(sa, 8)
    SSET(sb, 7)   SLOAD(sb, 9)

    RSET(0) RSET(1) RSET(2) RSET(3) RSET(4) RSET(5)   // AGPR phase hides loads

    SSET(sa, 8)   SLOAD(sa, 10)
    SSET(sb, 9)   SLOAD(sb, 11)

    LSET(0) LSET(1)

    SSET(sa, 10)  SLOAD(sa, 6)    // next step's set 6 (flies over barriers)
    SSET(sb, 11)  SLOAD(sb, 7)    // next step's set 7

    LSET(2) LSET(3)

    sync_lgkm();  // all A-reads done; safe to overwrite Ah

    EPI(0) EPI(1) EPI(2) EPI(3)

    sync_lgkm();  // new h visible for next step
  }

  __syncthreads();  // drain everything (incl. dangling prefetch)

  // logits = h_T @ W_hy + b_y; h_T read from Ah (f16, frag layout):
  // element (m,k) at Ah[(k>>5)*512 + ((k>>3)&3)*128 + (k&7) + m*8].
  for (int idx = tid; idx < 16 * V_; idx += 512) {
    int m = idx / V_, v = idx - m * V_;
    float s = by[v];
#pragma unroll 8
    for (int k = 0; k < H_; ++k) {
      float hk = (float)Ah[(k >> 5) * 512 + ((k >> 3) & 3) * 128 + (k & 7) + m * 8];
      s += hk * Why[k * V_ + v];
    }
    out[(r0 + m) * V_ + v] = s;
  }
}

extern "C" void kernel_launch(void* const* d_in, const int* in_sizes, int n_in,
                              void* d_out, int out_size, void* d_ws, size_t ws_size,
                              hipStream_t stream) {
  const int* X = (const int*)d_in[0];         // [1024,256] int32
  const float* Wemb = (const float*)d_in[1];  // [115,128]
  const float* Wxh = (const float*)d_in[2];   // [128,512]
  const float* Whh = (const float*)d_in[3];   // [512,512]
  const float* bh = (const float*)d_in[4];    // [512]
  const float* Why = (const float*)d_in[5];   // [512,115]
  const float* by = (const float*)d_in[6];    // [115]
  float* out = (float*)d_out;                 // [1024,115]

  char* ws = (char*)d_ws;
  float* Txh = (float*)ws;                        // 235,520 B
  _Float16* Wf = (_Float16*)(ws + 256 * 1024);    // 512 KB

  prep_table<<<dim3(V_), dim3(H_), 0, stream>>>(Wemb, Wxh, bh, Txh);
  prep_wf<<<dim3(1024), dim3(256), 0, stream>>>(Whh, Wf);
  rnn_main<<<dim3(64), dim3(512), 0, stream>>>(X, Txh, Wf, Why, by, out);
}

// Round 11
// 630.214 us; speedup vs baseline: 2.9371x; 1.5618x over previous
//
#include <hip/hip_runtime.h>

// RNN on MI355X: h_{t+1} = tanh(table[X[:,t]] + h_t @ W_hh), T=256, B=1024, H=512.
// Round 11: CONCURRENCY. r10's 9,200 cyc/step == sum(MFMA 2.5k, LDS ~2.5k,
// stream 3.1k, VALU ~4k) -> zero overlap at 2 waves/SIMD + 2 barriers.
//  - 16 waves x 32 cols (1024 thr) -> 4 waves/SIMD: phases of different waves
//    overlap. Ask/wave ~48 AGPR + ~65 arch = 113 <= 128 budget (no spill).
//  - ONE barrier/step: ping-pong Ah[2] (read cur, write cur^1).
//    LDS = 32 KB Ah + 128 KB WL = exactly 160 KB; X prefetched from L2.
//  - W split/wave: sets 0..5 AGPR (pinned), 6..11 streamed (192 KB/CU/step,
//    2-buffer rotation over the barrier), 12..15 in WL LDS.
//  - tanh = 1 - 2*rcp(exp2(2*log2e*x)+1): 5 VALU, no div sequence.
// f16 single-term MFMA builtins: absmax ~0.0078 (threshold 0.0534).

typedef __attribute__((ext_vector_type(4))) float f32x4;
typedef __attribute__((ext_vector_type(8))) _Float16 f16x8;

#define T_ 256
#define E_ 128
#define H_ 512
#define V_ 115

__device__ __forceinline__ float tanh_fast(float x) {
  // tanh(x) = 1 - 2/(e^{2x}+1); exp2(inf)->inf->rcp 0->1; exp2(-inf)->0->-1
  float e = __builtin_exp2f(x * 2.8853900817779268f);  // 2*log2(e)
  return 1.0f - 2.0f * __builtin_amdgcn_rcpf(e + 1.0f);
}

// lgkm-only barrier: global (W-stream, X, gather) loads stay in flight.
__device__ __forceinline__ void sync_lgkm() {
  asm volatile("s_waitcnt lgkmcnt(0)" ::: "memory");
  __builtin_amdgcn_s_barrier();
}

// table[v][h] = b_h[h] + sum_e W_emb[v][e] * W_xh[e][h]   (115 x 512, f32)
__global__ void prep_table(const float* __restrict__ Wemb, const float* __restrict__ Wxh,
                           const float* __restrict__ bh, float* __restrict__ Txh) {
  int v = blockIdx.x;
  int h = threadIdx.x;
  float s = bh[h];
  const float* we = Wemb + v * E_;
#pragma unroll 8
  for (int e = 0; e < E_; ++e) s += we[e] * Wxh[e * H_ + h];
  Txh[v * H_ + h] = s;
}

// Wf layout (f16): frag (nb=n>>4, kc=k>>5) is a contiguous 1KB block of 64
// lanes x 16B; lane (lg*16+lm) holds col n=nb*16+lm, k=kc*32+lg*8..+8.
__global__ void prep_wf(const float* __restrict__ Whh, _Float16* __restrict__ Wf) {
  int idx = blockIdx.x * 256 + threadIdx.x;  // 512*512
  int k = idx >> 9, n = idx & 511;
  float w = Whh[k * H_ + n];
  int nb = n >> 4, lm = n & 15, kc = k >> 5, lg = (k >> 3) & 3, kk = k & 7;
  Wf[(((nb * 16 + kc) * 4 + lg) * 16 + lm) * 8 + kk] = (_Float16)w;
}

// W frag (f, set s) for wave with col-block base nb0 (f in {0,1})
#define WG(f, s) (((const f16x8*)Wf)[(((nb0 + (f)) * 16 + (s)) << 6) + lane])

// AGPR-resident W: sets 0..5 x 2 frags = 48 AGPRs/wave, pinned once.
#define DECL2(s) f16x8 W##s##_0 = WG(0, s), W##s##_1 = WG(1, s);
#define PIN2(s)  asm volatile("" : "+a"(W##s##_0), "+a"(W##s##_1));

#define MMB(ac, a8, wv) \
  ac = __builtin_amdgcn_mfma_f32_16x16x32_f16(a8, wv, ac, 0, 0, 0);

#define RSET(s) {                                                  \
  f16x8 a8 = *(const f16x8*)(acur + (s) * 512 + lane * 8);         \
  MMB(acc0, a8, W##s##_0) MMB(acc1, a8, W##s##_1) }

// streamed-set consume / refill (buf = f16x8[2] = 8 arch regs)
#define SSET(buf, s) {                                             \
  f16x8 a8 = *(const f16x8*)(acur + (s) * 512 + lane * 8);         \
  MMB(acc0, a8, buf[0]) MMB(acc1, a8, buf[1]) }
#define SLOAD(buf, s) { buf[0] = WG(0, s); buf[1] = WG(1, s); }

// LDS-resident sets 12..15: WL block bi = w*8 + j*2 + f (1 KB each)
#define LSET(j) {                                                  \
  f16x8 a8 = *(const f16x8*)(acur + (12 + (j)) * 512 + lane * 8);  \
  const f16x8* wp = (const f16x8*)WL + ((w * 8 + (j) * 2) << 6) + lane; \
  f16x8 q0 = wp[0], q1 = wp[64];                                   \
  MMB(acc0, a8, q0) MMB(acc1, a8, q1) }

// tanh + scatter new h into Ah[nxt] (A-frag layout); no global stores.
#define EPI(f) {                                                   \
  int n = w * 32 + (f) * 16 + lm;                                  \
  int bidx = (n >> 5) * 512 + ((n >> 3) & 3) * 128 + (n & 7);      \
  _Pragma("unroll")                                                \
  for (int r = 0; r < 4; ++r) {                                    \
    float hv = tanh_fast(acc##f[r]);                               \
    anxt[bidx + (lg * 4 + r) * 8] = (_Float16)hv;                  \
  } }

__global__ __launch_bounds__(1024, 4)
void rnn_main(const int* __restrict__ X, const float* __restrict__ Txh,
              const _Float16* __restrict__ Wf, const float* __restrict__ Why,
              const float* __restrict__ by, float* __restrict__ out) {
  __shared__ _Float16 Ah[2][16 * H_];   // 32 KB: h ping-pong (A-frag layout)
  __shared__ _Float16 WL[65536];        // 128 KB: W sets 12..15, all 16 waves

  const int tid = threadIdx.x;
  const int lane = tid & 63;
  const int w = tid >> 6;          // wave 0..15; owns cols [w*32, w*32+32)
  const int nb0 = w * 2;
  const int r0 = blockIdx.x * 16;
  const int lm = lane & 15;
  const int lg = lane >> 4;

  // h0 = 0 (buffer 0 only; buffer 1 is written before first read)
  for (int i = tid; i < 16 * H_ / 2; i += 1024) ((int*)Ah[0])[i] = 0;
  // Stage W sets 12..15 into WL (one time, 128 KB). bi = w*8 + j*2 + f.
  for (int i = tid; i < 8192; i += 1024) {
    int bi = i >> 6, ln = i & 63;
    int w8 = bi >> 3, rem = bi & 7, j = rem >> 1, f = rem & 1;
    int nb = w8 * 2 + f;
    ((f16x8*)WL)[(bi << 6) + ln] =
        ((const f16x8*)Wf)[((nb * 16 + 12 + j) << 6) + ln];
  }

  // AGPR-resident W: sets 0..5 -> 48 AGPRs/wave, loaded once, pinned.
  DECL2(0) DECL2(1) DECL2(2) DECL2(3) DECL2(4) DECL2(5)
  PIN2(0) PIN2(1) PIN2(2) PIN2(3) PIN2(4) PIN2(5)

  // Prime the stream double-buffer: sa <- set 6, sb <- set 7.
  f16x8 sa[2], sb[2];
  SLOAD(sa, 6)
  SLOAD(sb, 7)

  // per-lane loop-invariant bases
  const float* txl = Txh + w * 32 + lm;            // gather base
  const int* xrow = X + (r0 + lg * 4) * T_;        // 4 X rows at imm offsets

  // X indices for t=0
  int vx0 = xrow[0 * T_], vx1 = xrow[1 * T_], vx2 = xrow[2 * T_], vx3 = xrow[3 * T_];

  const _Float16* acur = Ah[0];
  _Float16* anxt = Ah[1];

  __syncthreads();

  for (int t = 0; t < T_; ++t) {
    // acc := xh  (gather straight into the MFMA C-operand)
    f32x4 acc0, acc1;
    {
      const float* g0 = txl + vx0 * H_;
      const float* g1 = txl + vx1 * H_;
      const float* g2 = txl + vx2 * H_;
      const float* g3 = txl + vx3 * H_;
      acc0[0]=g0[0];  acc0[1]=g1[0];  acc0[2]=g2[0];  acc0[3]=g3[0];
      acc1[0]=g0[16]; acc1[1]=g1[16]; acc1[2]=g2[16]; acc1[3]=g3[16];
    }
    // prefetch next step's X indices (L2; consumed next iteration)
    {
      int tn = (t + 1) & (T_ - 1);
      vx0 = xrow[tn];
      vx1 = xrow[1 * T_ + tn];
      vx2 = xrow[2 * T_ + tn];
      vx3 = xrow[3 * T_ + tn];
    }

    // Stream rotation (consume prefetched, issue 2 sets ahead).
    SSET(sa, 6)   SLOAD(sa, 8)
    SSET(sb, 7)   SLOAD(sb, 9)

    RSET(0) RSET(1) RSET(2) RSET(3) RSET(4) RSET(5)   // AGPR phase hides loads

    SSET(sa, 8)   SLOAD(sa, 10)
    SSET(sb, 9)   SLOAD(sb, 11)

    LSET(0) LSET(1)

    SSET(sa, 10)  SLOAD(sa, 6)    // next step's set 6 (flies over barrier)
    SSET(sb, 11)  SLOAD(sb, 7)    // next step's set 7

    LSET(2) LSET(3)

    // write new h into the OTHER buffer, then one barrier
    EPI(0) EPI(1)

    sync_lgkm();

    const _Float16* tmp = acur; acur = anxt; anxt = (_Float16*)tmp;
  }

  // h_T is in Ah[0] (256 swaps). logits = h_T @ W_hy + b_y.
  for (int idx = tid; idx < 16 * V_; idx += 1024) {
    int m = idx / V_, v = idx - m * V_;
    float s = by[v];
#pragma unroll 8
    for (int k = 0; k < H_; ++k) {
      float hk = (float)Ah[0][(k >> 5) * 512 + ((k >> 3) & 3) * 128 + (k & 7) + m * 8];
      s += hk * Why[k * V_ + v];
    }
    out[(r0 + m) * V_ + v] = s;
  }
}

extern "C" void kernel_launch(void* const* d_in, const int* in_sizes, int n_in,
                              void* d_out, int out_size, void* d_ws, size_t ws_size,
                              hipStream_t stream) {
  const int* X = (const int*)d_in[0];         // [1024,256] int32
  const float* Wemb = (const float*)d_in[1];  // [115,128]
  const float* Wxh = (const float*)d_in[2];   // [128,512]
  const float* Whh = (const float*)d_in[3];   // [512,512]
  const float* bh = (const float*)d_in[4];    // [512]
  const float* Why = (const float*)d_in[5];   // [512,115]
  const float* by = (const float*)d_in[6];    // [115]
  float* out = (float*)d_out;                 // [1024,115]

  char* ws = (char*)d_ws;
  float* Txh = (float*)ws;                        // 235,520 B
  _Float16* Wf = (_Float16*)(ws + 256 * 1024);    // 512 KB

  prep_table<<<dim3(V_), dim3(H_), 0, stream>>>(Wemb, Wxh, bh, Txh);
  prep_wf<<<dim3(1024), dim3(256), 0, stream>>>(Whh, Wf);
  rnn_main<<<dim3(64), dim3(1024), 0, stream>>>(X, Txh, Wf, Why, by, out);
}